// Round 1
// baseline (1181.964 us; speedup 1.0000x reference)
//
#include <hip/hip_runtime.h>
#include <math.h>

#define N_NODES 50000
#define N_EDGES 1600000

// ---------------- node inverse L2 norm: TPN lanes per node ----------------
template<int F, int TPN>
__global__ void norm_kernel(const float* __restrict__ x, float* __restrict__ nrminv) {
    int gid = blockIdx.x * blockDim.x + threadIdx.x;
    int node = gid / TPN;
    int t = gid % TPN;
    if (node >= N_NODES) return;
    const float* row = x + (size_t)node * F;
    float s = 0.f;
    constexpr int CHUNKS = F / (TPN * 4);
    #pragma unroll
    for (int c = 0; c < CHUNKS; c++) {
        float4 v = *(const float4*)(row + c * TPN * 4 + t * 4);
        s += v.x*v.x + v.y*v.y + v.z*v.z + v.w*v.w;
    }
    #pragma unroll
    for (int m = TPN/2; m >= 1; m >>= 1) s += __shfl_xor(s, m);
    if (t == 0) {
        float n = sqrtf(s);
        nrminv[node] = (n == 0.f) ? 1.f : 1.f / n;
    }
}

// ------------- per-edge cosine sim + threshold + rowsum/deg count -------------
template<int F, int TPE>
__global__ void edge_sim_kernel(const float* __restrict__ x,
                                const float* __restrict__ nrminv,
                                const int* __restrict__ src, const int* __restrict__ dst,
                                float* __restrict__ w_e,
                                float* __restrict__ rowsum, float* __restrict__ degcnt) {
    int gid = blockIdx.x * blockDim.x + threadIdx.x;
    int e = gid / TPE;
    int t = gid % TPE;
    if (e >= N_EDGES) return;
    int s = src[e], d = dst[e];
    const float* rs = x + (size_t)s * F;
    const float* rd = x + (size_t)d * F;
    float acc = 0.f;
    constexpr int CHUNKS = F / (TPE * 4);
    #pragma unroll
    for (int c = 0; c < CHUNKS; c++) {
        float4 a = *(const float4*)(rs + c * TPE * 4 + t * 4);
        float4 b = *(const float4*)(rd + c * TPE * 4 + t * 4);
        acc += a.x*b.x + a.y*b.y + a.z*b.z + a.w*b.w;
    }
    #pragma unroll
    for (int m = TPE/2; m >= 1; m >>= 1) acc += __shfl_xor(acc, m);
    if (t == 0) {
        float sim = acc * nrminv[s] * nrminv[d];
        float w = (s != d && sim >= 0.5f) ? sim : 0.f;
        w_e[e] = w;
        if (w != 0.f) {
            atomicAdd(&rowsum[s], w);     // w >= 0.5 so |w| == w
            atomicAdd(&degcnt[s], 1.f);
        }
    }
}

// ------------- self_w = 1/(deg+1); seed deg2 with self_w -------------
__global__ void selfw_kernel(const float* __restrict__ degcnt,
                             float* __restrict__ selfw, float* __restrict__ deg2) {
    int i = blockIdx.x * blockDim.x + threadIdx.x;
    if (i >= N_NODES) return;
    float sw = 1.f / (degcnt[i] + 1.f);
    selfw[i] = sw;
    deg2[i] = sw;
}

// ------------- L1 row-normalize w; accumulate incoming deg2 at dst -------------
__global__ void edge_norm_kernel(const int* __restrict__ src, const int* __restrict__ dst,
                                 const float* __restrict__ rowsum,
                                 float* __restrict__ w_e, float* __restrict__ deg2) {
    int e = blockIdx.x * blockDim.x + threadIdx.x;
    if (e >= N_EDGES) return;
    float w = w_e[e];
    if (w != 0.f) {
        float wn = w / rowsum[src[e]];   // rowsum >= w > 0 here
        w_e[e] = wn;
        atomicAdd(&deg2[dst[e]], wn);
    }
}

// ------------- dinv = rsqrt(deg2); deg2 > 0 always (self_w > 0) -------------
__global__ void dinv_kernel(const float* __restrict__ deg2, float* __restrict__ dinv) {
    int i = blockIdx.x * blockDim.x + threadIdx.x;
    if (i >= N_NODES) return;
    dinv[i] = rsqrtf(deg2[i]);
}

// ------------- h = x @ W  (W fully LDS-resident; thread computes 4 cols) -------------
template<int FIN, int FOUT>
__global__ void gemm_kernel(const float* __restrict__ x, const float* __restrict__ W,
                            float* __restrict__ h) {
    __shared__ float Wlds[FIN * FOUT];
    for (int i = threadIdx.x; i < FIN * FOUT; i += blockDim.x) Wlds[i] = W[i];
    __syncthreads();
    constexpr int C4 = FOUT / 4;
    int idx = blockIdx.x * blockDim.x + threadIdx.x;
    int row = idx / C4;
    int c4 = idx % C4;
    if (row >= N_NODES) return;
    const float* xr = x + (size_t)row * FIN;
    float4 acc = make_float4(0.f, 0.f, 0.f, 0.f);
    #pragma unroll 4
    for (int k = 0; k < FIN; k++) {
        float xv = xr[k];
        float4 w4 = *(const float4*)&Wlds[k * FOUT + c4 * 4];
        acc.x += xv * w4.x;
        acc.y += xv * w4.y;
        acc.z += xv * w4.z;
        acc.w += xv * w4.w;
    }
    *(float4*)&h[(size_t)row * FOUT + c4 * 4] = acc;
}

// ------------- scatter: out[dst] += dinv[s]*w*dinv[d] * h[src] -------------
template<int FOUT, int TPE>
__global__ void edge_scatter_kernel(const int* __restrict__ src, const int* __restrict__ dst,
                                    const float* __restrict__ w_e,
                                    const float* __restrict__ dinv,
                                    const float* __restrict__ h,
                                    float* __restrict__ out) {
    int gid = blockIdx.x * blockDim.x + threadIdx.x;
    int e = gid / TPE;
    int t = gid % TPE;
    if (e >= N_EDGES) return;
    float w = w_e[e];
    if (w == 0.f) return;
    int s = src[e], d = dst[e];
    float coeff = dinv[s] * w * dinv[d];
    const float* hs = h + (size_t)s * FOUT;
    float* od = out + (size_t)d * FOUT;
    constexpr int EPT = FOUT / TPE;
    #pragma unroll
    for (int i = 0; i < EPT; i++) {
        int j = i * TPE + t;             // interleaved: coalesced h reads
        atomicAdd(&od[j], coeff * hs[j]);
    }
}

// ------------- epilogue: + self term + bias (+ ReLU), in place -------------
template<int FOUT, bool RELU>
__global__ void epilogue_kernel(const float* __restrict__ h, const float* __restrict__ b,
                                const float* __restrict__ selfw, const float* __restrict__ dinv,
                                float* __restrict__ out) {
    int idx = blockIdx.x * blockDim.x + threadIdx.x;
    if (idx >= N_NODES * FOUT) return;
    int n = idx / FOUT;
    int j = idx % FOUT;
    float di = dinv[n];
    float v = out[idx] + selfw[n] * di * di * h[idx] + b[j];
    if (RELU) v = fmaxf(v, 0.f);
    out[idx] = v;
}

// ------------- log_softmax over 40 classes: one wave per row -------------
__global__ void logsoftmax_kernel(const float* __restrict__ in, float* __restrict__ out) {
    int gid = blockIdx.x * blockDim.x + threadIdx.x;
    int row = gid / 64;
    int lane = threadIdx.x % 64;
    if (row >= N_NODES) return;
    const float* r = in + (size_t)row * 40;
    float v = (lane < 40) ? r[lane] : -INFINITY;
    float m = v;
    #pragma unroll
    for (int s = 32; s >= 1; s >>= 1) m = fmaxf(m, __shfl_xor(m, s));
    float ex = (lane < 40) ? expf(v - m) : 0.f;
    float sum = ex;
    #pragma unroll
    for (int s = 32; s >= 1; s >>= 1) sum += __shfl_xor(sum, s);
    float lse = m + logf(sum);
    if (lane < 40) out[(size_t)row * 40 + lane] = v - lse;
}

// =================== host orchestration ===================
template<int FIN, int FOUT, int TPN, int TPE_SIM, int TPE_SC, bool RELU>
static void run_layer(const float* x, const int* src, const int* dst,
                      const float* W, const float* b,
                      float* out, float* h, float* w_e,
                      float* nrminv, float* rowsum, float* degcnt,
                      float* deg2, float* dinv, float* selfw,
                      hipStream_t stream) {
    const int BS = 256;
    hipMemsetAsync(rowsum, 0, N_NODES * sizeof(float), stream);
    hipMemsetAsync(degcnt, 0, N_NODES * sizeof(float), stream);

    norm_kernel<FIN, TPN><<<(N_NODES * TPN + BS - 1) / BS, BS, 0, stream>>>(x, nrminv);

    long sim_threads = (long)N_EDGES * TPE_SIM;
    edge_sim_kernel<FIN, TPE_SIM><<<(int)((sim_threads + BS - 1) / BS), BS, 0, stream>>>(
        x, nrminv, src, dst, w_e, rowsum, degcnt);

    selfw_kernel<<<(N_NODES + BS - 1) / BS, BS, 0, stream>>>(degcnt, selfw, deg2);

    edge_norm_kernel<<<(N_EDGES + BS - 1) / BS, BS, 0, stream>>>(src, dst, rowsum, w_e, deg2);

    dinv_kernel<<<(N_NODES + BS - 1) / BS, BS, 0, stream>>>(deg2, dinv);

    gemm_kernel<FIN, FOUT><<<(N_NODES * (FOUT / 4) + BS - 1) / BS, BS, 0, stream>>>(x, W, h);

    hipMemsetAsync(out, 0, (size_t)N_NODES * FOUT * sizeof(float), stream);

    long sc_threads = (long)N_EDGES * TPE_SC;
    edge_scatter_kernel<FOUT, TPE_SC><<<(int)((sc_threads + BS - 1) / BS), BS, 0, stream>>>(
        src, dst, w_e, dinv, h, out);

    epilogue_kernel<FOUT, RELU><<<(N_NODES * FOUT + BS - 1) / BS, BS, 0, stream>>>(
        h, b, selfw, dinv, out);
}

extern "C" void kernel_launch(void* const* d_in, const int* in_sizes, int n_in,
                              void* d_out, int out_size, void* d_ws, size_t ws_size,
                              hipStream_t stream) {
    const float* x0 = (const float*)d_in[0];
    const int* ei   = (const int*)d_in[1];
    const int* src  = ei;
    const int* dst  = ei + N_EDGES;
    const float* W1 = (const float*)d_in[2];
    const float* b1 = (const float*)d_in[3];
    const float* W2 = (const float*)d_in[4];
    const float* b2 = (const float*)d_in[5];
    const float* W3 = (const float*)d_in[6];
    const float* b3 = (const float*)d_in[7];
    float* out = (float*)d_out;

    // workspace layout (floats): ~17.6M floats = ~70 MB
    float* ws     = (float*)d_ws;
    float* xbuf1  = ws;                        // 50000*128 = 6,400,000
    float* h      = xbuf1 + 6400000;           // 6,400,000
    float* w_e    = h + 6400000;               // 1,600,000
    float* xbuf2  = w_e + 1600000;             // 50000*16 = 800,000
    float* tmp3   = xbuf2 + 800000;            // 50000*40 = 2,000,000
    float* nrminv = tmp3 + 2000000;            // 50,000
    float* rowsum = nrminv + 50000;
    float* degcnt = rowsum + 50000;
    float* deg2   = degcnt + 50000;
    float* dinv   = deg2 + 50000;
    float* selfw  = dinv + 50000;

    // Layer 0: 128 -> 128, ReLU
    run_layer<128, 128, 16, 16, 16, true>(x0, src, dst, W1, b1, xbuf1, h, w_e,
                                          nrminv, rowsum, degcnt, deg2, dinv, selfw, stream);
    // Layer 1: 128 -> 16, ReLU
    run_layer<128, 16, 16, 16, 8, true>(xbuf1, src, dst, W2, b2, xbuf2, h, w_e,
                                        nrminv, rowsum, degcnt, deg2, dinv, selfw, stream);
    // Layer 2: 16 -> 40, no ReLU
    run_layer<16, 40, 4, 4, 8, false>(xbuf2, src, dst, W3, b3, tmp3, h, w_e,
                                      nrminv, rowsum, degcnt, deg2, dinv, selfw, stream);

    logsoftmax_kernel<<<(N_NODES * 64 + 255) / 256, 256, 0, stream>>>(tmp3, out);
}